// Round 4
// baseline (269.705 us; speedup 1.0000x reference)
//
#include <hip/hip_runtime.h>
#include <hip/hip_fp16.h>

#define NDIM 8192
#define KDIM 8192
#define NT 256          // N / 32 hash tiles
#define MOD2 4193281    // HASH_SIZE - 32*32 + 1
#define PRIME 2038074743LL

#define BM 256
#define BN 128
#define BK 32
#define SPLITK 4
#define KITER 64        // (KDIM/SPLITK)/BK
#define BSLAB 1032      // halves per k-octet slab: 128*8 + 8 pad (bank offset 4/oct)

typedef _Float16 half8 __attribute__((ext_vector_type(8)));
typedef float floatx4 __attribute__((ext_vector_type(4)));

// ---------------- prepass 1: fp32 -> fp16 for x and hashed_weight ----------------
__global__ __launch_bounds__(256) void cvt_kernel(const float* __restrict__ x,
                                                  const float* __restrict__ hw,
                                                  __half* __restrict__ xh,
                                                  __half* __restrict__ hh) {
    int i = blockIdx.x * 256 + threadIdx.x;   // 0 .. 2M-1, each handles 4 floats
    const float4* s;
    __half2* d;
    int j;
    if (i < (1 << 20)) { s = (const float4*)x;  d = (__half2*)xh; j = i; }
    else               { s = (const float4*)hw; d = (__half2*)hh; j = i - (1 << 20); }
    float4 v = s[j];
    d[j * 2]     = __floats2half2_rn(v.x, v.y);
    d[j * 2 + 1] = __floats2half2_rn(v.z, v.w);
}

// ---------------- prepass 2: tile start offsets (ROBE-Z hash) ----------------
__global__ __launch_bounds__(256) void starts_kernel(const int* __restrict__ rn,
                                                     int* __restrict__ starts) {
    bool is64 = (rn[1] == 0 && rn[3] == 0);
    long long R1 = is64 ? rn[2] : rn[1];
    long long R2 = is64 ? rn[4] : rn[2];
    long long R3 = is64 ? rn[6] : rn[3];
    int t = blockIdx.x * 256 + threadIdx.x;   // 0 .. 65535
    long long k_id = t >> 8;
    long long n_id = t & 255;
    long long v = (k_id * R3 + n_id * R2 + R1) % PRIME;
    starts[t] = (int)(v % MOD2);
}

// ---------------- prepass 3: out = bias (split-K blocks atomicAdd into it) ----------------
__global__ __launch_bounds__(256) void init_kernel(const float* __restrict__ bias,
                                                   float* __restrict__ out) {
    int i = blockIdx.x * 256 + threadIdx.x;   // 1M float4s
    float4 b = *(const float4*)(bias + ((i & 2047) << 2));
    ((float4*)out)[i] = b;
}

// ---------------- main GEMM: split-K=4, 256x128 block, A direct-from-global ----------------
__global__ __launch_bounds__(512, 4) void gemm_kernel(
    const __half* __restrict__ xh, const __half* __restrict__ hh,
    const int* __restrict__ starts, float* __restrict__ out) {
    __shared__ __align__(16) __half Bs[2][4 * BSLAB];   // [k-octet][n][8] k-runs
    __shared__ int Ss[KITER * 4];                       // per-block starts table

    const int tid = threadIdx.x;
    const int lane = tid & 63;
    const int wave = tid >> 6;       // 0..7
    const int wm = wave >> 1;        // 0..3 : 64-row strip
    const int wn = wave & 1;         // 0..1 : 64-col strip
    const int quad = lane >> 4;
    const int l16 = lane & 15;

    // block decode: same (m_blk, ks) per XCD -> A panel L2-local
    const int i = blockIdx.x;        // 512 blocks
    const int ks = i & 3;
    const int m_blk = (i >> 2) & 1;
    const int n_blk = i >> 3;        // 0..63
    const int gm0 = m_blk * BM;
    const int gn0 = n_blk * BN;
    const int kt0 = ks * KITER;
    const int n_id0 = n_blk * 4;     // 4 hash tiles per block

    if (tid < KITER * 4) {
        int kp = tid >> 2, tile = tid & 3;
        Ss[tid] = starts[(kt0 + kp) * NT + n_id0 + tile];
    }

    // B staging roles: thread covers 2 n x 4 k of one 32x32 hash tile
    const int b_tile = tid >> 7;              // 0..3
    const int t7 = tid & 127;
    const int b_np = t7 & 15;                 // n-pair
    const int b_kg = t7 >> 4;                 // 0..7 : 4-k group
    const int b_oct = b_kg >> 1;
    const int b_base = b_oct * BSLAB + (b_tile * 32 + 2 * b_np) * 8 + (b_kg & 1) * 4;

    // A fragment base: row gm0 + wm*64 + l16 (+r*16), col kt0*32 + quad*8 (+kp*32)
    const __half* apbase = xh + (size_t)(gm0 + wm * 64 + l16) * KDIM + kt0 * 32 + quad * 8;

    unsigned int pb0, pb1, pb2, pb3;

#define LOADB(kp_) do {                                                        \
        int st = Ss[(kp_) * 4 + b_tile];                                       \
        const __half* src = hh + st + b_kg * 128 + b_np * 2;                   \
        pb0 = *(const unsigned int*)(src);                                     \
        pb1 = *(const unsigned int*)(src + 32);                                \
        pb2 = *(const unsigned int*)(src + 64);                                \
        pb3 = *(const unsigned int*)(src + 96);                                \
    } while (0)

#define STOREB(buf_) do {                                                      \
        unsigned int lo0 = (pb0 & 0xffffu) | (pb1 << 16);                      \
        unsigned int lo1 = (pb2 & 0xffffu) | (pb3 << 16);                      \
        unsigned int hi0 = (pb0 >> 16) | (pb1 & 0xffff0000u);                  \
        unsigned int hi1 = (pb2 >> 16) | (pb3 & 0xffff0000u);                  \
        uint2 e = {lo0, lo1}, o = {hi0, hi1};                                  \
        *(uint2*)&Bs[buf_][b_base] = e;                                        \
        *(uint2*)&Bs[buf_][b_base + 8] = o;                                    \
    } while (0)

    floatx4 acc[4][4];
#pragma unroll
    for (int r = 0; r < 4; r++)
#pragma unroll
        for (int c = 0; c < 4; c++)
            acc[r][c] = (floatx4){0.f, 0.f, 0.f, 0.f};

    __syncthreads();                  // Ss visible
    LOADB(0);
    STOREB(0);
    __syncthreads();

    int cur = 0;
    for (int kp = 0; kp < KITER; kp++) {
        // A fragments: direct global (L2-resident), issued first so MFMA's
        // vmcnt wait does NOT drain the next-tile B loads issued after.
        half8 af[4];
        const __half* ap = apbase + kp * 32;
#pragma unroll
        for (int r = 0; r < 4; r++)
            af[r] = *(const half8*)(ap + r * 16 * KDIM);

        if (kp + 1 < KITER) LOADB(kp + 1);   // next B tile, stays in flight

        half8 bf[4];
#pragma unroll
        for (int c = 0; c < 4; c++)
            bf[c] = *(const half8*)&Bs[cur][quad * BSLAB + (wn * 64 + c * 16 + l16) * 8];

#pragma unroll
        for (int r = 0; r < 4; r++)
#pragma unroll
            for (int c = 0; c < 4; c++)
                acc[r][c] = __builtin_amdgcn_mfma_f32_16x16x32_f16(af[r], bf[c], acc[r][c], 0, 0, 0);

        if (kp + 1 < KITER) STOREB(cur ^ 1); // vmcnt wait lands after MFMA
        __syncthreads();
        cur ^= 1;
    }

    // ---- epilogue: atomic accumulate (C/D layout col=lane&15, row=quad*4+reg) ----
#pragma unroll
    for (int c = 0; c < 4; c++) {
        int col = gn0 + wn * 64 + c * 16 + l16;
#pragma unroll
        for (int r = 0; r < 4; r++) {
            int row0 = gm0 + wm * 64 + r * 16 + quad * 4;
#pragma unroll
            for (int e = 0; e < 4; e++)
                atomicAdd(&out[(size_t)(row0 + e) * NDIM + col], acc[r][c][e]);
        }
    }
#undef LOADB
#undef STOREB
}

extern "C" void kernel_launch(void* const* d_in, const int* in_sizes, int n_in,
                              void* d_out, int out_size, void* d_ws, size_t ws_size,
                              hipStream_t stream) {
    const float* x = (const float*)d_in[0];
    const float* hw = (const float*)d_in[1];
    const float* bias = (const float*)d_in[2];
    const int* rn = (const int*)d_in[3];
    float* out = (float*)d_out;

    char* ws = (char*)d_ws;
    __half* xh = (__half*)ws;                          // 8 MB : x as f16
    __half* hh = (__half*)(ws + (8u << 20));           // 8 MB : hashed_weight as f16
    int* starts = (int*)(ws + (16u << 20));            // 256 KB : tile start table

    hipLaunchKernelGGL(cvt_kernel, dim3(8192), dim3(256), 0, stream, x, hw, xh, hh);
    hipLaunchKernelGGL(starts_kernel, dim3(256), dim3(256), 0, stream, rn, starts);
    hipLaunchKernelGGL(init_kernel, dim3(4096), dim3(256), 0, stream, bias, out);
    hipLaunchKernelGGL(gemm_kernel, dim3(512), dim3(512), 0, stream, xh, hh, starts, out);
}

// Round 5
// 207.377 us; speedup vs baseline: 1.3006x; 1.3006x over previous
//
#include <hip/hip_runtime.h>
#include <hip/hip_fp16.h>

#define NDIM 8192
#define KDIM 8192
#define NT 256          // N / 32 hash tiles
#define MOD2 4193281    // HASH_SIZE - 32*32 + 1
#define PRIME 2038074743LL

#define BM 256
#define BN 128
#define BK 32
#define SPLITK 4
#define KITER 64        // (KDIM/SPLITK)/BK
#define ASTRIDE 40      // halves per A row (32 + 8 pad; 2-way bank alias = free)
#define BSLAB 1032      // halves per k-octet slab (128*8 + 4 pad dwords -> all 32 banks)

typedef _Float16 half8 __attribute__((ext_vector_type(8)));
typedef float floatx4 __attribute__((ext_vector_type(4)));

// ---------------- prepass 1: fp32 -> fp16 for x and hashed_weight ----------------
__global__ __launch_bounds__(256) void cvt_kernel(const float* __restrict__ x,
                                                  const float* __restrict__ hw,
                                                  __half* __restrict__ xh,
                                                  __half* __restrict__ hh) {
    int i = blockIdx.x * 256 + threadIdx.x;   // 0 .. 2M-1, each handles 4 floats
    const float4* s;
    __half2* d;
    int j;
    if (i < (1 << 20)) { s = (const float4*)x;  d = (__half2*)xh; j = i; }
    else               { s = (const float4*)hw; d = (__half2*)hh; j = i - (1 << 20); }
    float4 v = s[j];
    d[j * 2]     = __floats2half2_rn(v.x, v.y);
    d[j * 2 + 1] = __floats2half2_rn(v.z, v.w);
}

// ---------------- prepass 2: tile start offsets (ROBE-Z hash) ----------------
__global__ __launch_bounds__(256) void starts_kernel(const int* __restrict__ rn,
                                                     int* __restrict__ starts) {
    bool is64 = (rn[1] == 0 && rn[3] == 0);
    long long R1 = is64 ? rn[2] : rn[1];
    long long R2 = is64 ? rn[4] : rn[2];
    long long R3 = is64 ? rn[6] : rn[3];
    int t = blockIdx.x * 256 + threadIdx.x;   // 0 .. 65535
    long long k_id = t >> 8;
    long long n_id = t & 255;
    long long v = (k_id * R3 + n_id * R2 + R1) % PRIME;
    starts[t] = (int)(v % MOD2);
}

// ---------------- prepass 3: out = bias (split-K blocks atomicAdd into it) ----------------
__global__ __launch_bounds__(256) void init_kernel(const float* __restrict__ bias,
                                                   float* __restrict__ out) {
    int i = blockIdx.x * 256 + threadIdx.x;   // 1M float4s
    float4 b = *(const float4*)(bias + ((i & 2047) << 2));
    ((float4*)out)[i] = b;
}

// ---------------- main GEMM: split-K=4, 256x128 block, 64x64 wave tiles ----------------
__global__ __launch_bounds__(512, 4) void gemm_kernel(
    const __half* __restrict__ xh, const __half* __restrict__ hh,
    const int* __restrict__ starts, float* __restrict__ out) {
    __shared__ __align__(16) __half As[2][BM * ASTRIDE];   // [m][k] padded
    __shared__ __align__(16) __half Bs[2][4 * BSLAB];      // [k-octet][n][8] k-runs
    __shared__ int Ss[KITER * 4];                          // per-block starts table

    const int tid = threadIdx.x;
    const int lane = tid & 63;
    const int wave = tid >> 6;       // 0..7
    const int wm = wave >> 1;        // 0..3 : 64-row strip
    const int wn = wave & 1;         // 0..1 : 64-col strip
    const int quad = lane >> 4;
    const int l16 = lane & 15;

    // block decode: 8 consecutive blocks = all (ks, m_blk) for one n_blk
    // -> each XCD keeps one 1 MB A-panel L2-resident across n_blks
    const int i = blockIdx.x;        // 512 blocks
    const int ks = i & 3;
    const int m_blk = (i >> 2) & 1;
    const int n_blk = i >> 3;        // 0..63
    const int gm0 = m_blk * BM;
    const int gn0 = n_blk * BN;
    const int kt0 = ks * KITER;
    const int n_id0 = n_blk * 4;     // 4 hash tiles per block

    if (tid < KITER * 4) {
        int kp = tid >> 2, tile = tid & 3;
        Ss[tid] = starts[(kt0 + kp) * NT + n_id0 + tile];
    }

    // A staging: thread covers rows (tid>>2) and (tid>>2)+128, 16B chunk tid&3
    const int a_row = tid >> 2;               // 0..127
    const int a_ch = tid & 3;
    const __half* aptr = xh + (size_t)(gm0 + a_row) * KDIM + kt0 * 32 + a_ch * 8;

    // B staging: thread covers 2 n x 4 k of one 32x32 hash tile
    const int b_tile = tid >> 7;              // 0..3
    const int t7 = tid & 127;
    const int b_np = t7 & 15;                 // n-pair
    const int b_kg = t7 >> 4;                 // 0..7 : 4-k group
    const int b_oct = b_kg >> 1;
    const int b_base = b_oct * BSLAB + (b_tile * 32 + 2 * b_np) * 8 + (b_kg & 1) * 4;

    uint4 pa0, pa1;
    unsigned int pb0, pb1, pb2, pb3;

#define LOADT(kp_) do {                                                        \
        pa0 = *(const uint4*)(aptr + (kp_) * 32);                              \
        pa1 = *(const uint4*)(aptr + (size_t)128 * KDIM + (kp_) * 32);         \
        int st = Ss[(kp_) * 4 + b_tile];                                       \
        const __half* src = hh + st + b_kg * 128 + b_np * 2;                   \
        pb0 = *(const unsigned int*)(src);                                     \
        pb1 = *(const unsigned int*)(src + 32);                                \
        pb2 = *(const unsigned int*)(src + 64);                                \
        pb3 = *(const unsigned int*)(src + 96);                                \
    } while (0)

#define STORET(buf_) do {                                                      \
        *(uint4*)&As[buf_][a_row * ASTRIDE + a_ch * 8] = pa0;                  \
        *(uint4*)&As[buf_][(a_row + 128) * ASTRIDE + a_ch * 8] = pa1;          \
        unsigned int lo0 = (pb0 & 0xffffu) | (pb1 << 16);                      \
        unsigned int lo1 = (pb2 & 0xffffu) | (pb3 << 16);                      \
        unsigned int hi0 = (pb0 >> 16) | (pb1 & 0xffff0000u);                  \
        unsigned int hi1 = (pb2 >> 16) | (pb3 & 0xffff0000u);                  \
        uint2 e = {lo0, lo1}, o = {hi0, hi1};                                  \
        *(uint2*)&Bs[buf_][b_base] = e;                                        \
        *(uint2*)&Bs[buf_][b_base + 8] = o;                                    \
    } while (0)

    floatx4 acc[4][4];
#pragma unroll
    for (int r = 0; r < 4; r++)
#pragma unroll
        for (int c = 0; c < 4; c++)
            acc[r][c] = (floatx4){0.f, 0.f, 0.f, 0.f};

    __syncthreads();                  // Ss visible
    LOADT(0);
    STORET(0);
    __syncthreads();

    int cur = 0;
    for (int kp = 0; kp < KITER; kp++) {
        if (kp + 1 < KITER) LOADT(kp + 1);   // next tile into regs, stays in flight

        half8 af[4], bf[4];
#pragma unroll
        for (int r = 0; r < 4; r++) {
            int m = wm * 64 + r * 16 + l16;
            af[r] = *(const half8*)&As[cur][m * ASTRIDE + quad * 8];
        }
#pragma unroll
        for (int c = 0; c < 4; c++)
            bf[c] = *(const half8*)&Bs[cur][quad * BSLAB + (wn * 64 + c * 16 + l16) * 8];

#pragma unroll
        for (int r = 0; r < 4; r++)
#pragma unroll
            for (int c = 0; c < 4; c++)
                acc[r][c] = __builtin_amdgcn_mfma_f32_16x16x32_f16(af[r], bf[c], acc[r][c], 0, 0, 0);

        if (kp + 1 < KITER) STORET(cur ^ 1); // vmcnt wait lands after MFMA
        __syncthreads();
        cur ^= 1;
    }

    // ---- epilogue: atomic accumulate (C/D layout col=lane&15, row=quad*4+reg) ----
#pragma unroll
    for (int c = 0; c < 4; c++) {
        int col = gn0 + wn * 64 + c * 16 + l16;
#pragma unroll
        for (int r = 0; r < 4; r++) {
            int row0 = gm0 + wm * 64 + r * 16 + quad * 4;
#pragma unroll
            for (int e = 0; e < 4; e++)
                atomicAdd(&out[(size_t)(row0 + e) * NDIM + col], acc[r][c][e]);
        }
    }
#undef LOADT
#undef STORET
}

extern "C" void kernel_launch(void* const* d_in, const int* in_sizes, int n_in,
                              void* d_out, int out_size, void* d_ws, size_t ws_size,
                              hipStream_t stream) {
    const float* x = (const float*)d_in[0];
    const float* hw = (const float*)d_in[1];
    const float* bias = (const float*)d_in[2];
    const int* rn = (const int*)d_in[3];
    float* out = (float*)d_out;

    char* ws = (char*)d_ws;
    __half* xh = (__half*)ws;                          // 8 MB : x as f16
    __half* hh = (__half*)(ws + (8u << 20));           // 8 MB : hashed_weight as f16
    int* starts = (int*)(ws + (16u << 20));            // 256 KB : tile start table

    hipLaunchKernelGGL(cvt_kernel, dim3(8192), dim3(256), 0, stream, x, hw, xh, hh);
    hipLaunchKernelGGL(starts_kernel, dim3(256), dim3(256), 0, stream, rn, starts);
    hipLaunchKernelGGL(init_kernel, dim3(4096), dim3(256), 0, stream, bias, out);
    hipLaunchKernelGGL(gemm_kernel, dim3(512), dim3(512), 0, stream, xh, hh, starts, out);
}